// Round 1
// baseline (284.655 us; speedup 1.0000x reference)
//
#include <hip/hip_runtime.h>

// EdgeLoss: mean(|sobel_x(sr)-sobel_x(hr)| + |sobel_y(sr)-sobel_y(hr)|)
// Linearity: = mean(|sobel_x(d)| + |sobel_y(d)|), d = sr - hr.
// Separable sobel via 3-row register sliding window; float4 column strips.

#define IMG_H 1024
#define IMG_W 1024
#define IMG_B 32
#define CHUNK_H 32                 // output rows per thread pass
#define NCHUNK (IMG_H / CHUNK_H)   // 32

__device__ __forceinline__ void load_row(const float* __restrict__ sr,
                                         const float* __restrict__ hr,
                                         size_t img_off, int x0, int yin,
                                         float4& s, float4& t) {
    float dl = 0.f, dr = 0.f;
    float4 d = make_float4(0.f, 0.f, 0.f, 0.f);
    if ((unsigned)yin < (unsigned)IMG_H) {
        size_t row = img_off + (size_t)yin * IMG_W;
        const float4 a = *reinterpret_cast<const float4*>(sr + row + x0);
        const float4 b = *reinterpret_cast<const float4*>(hr + row + x0);
        d.x = a.x - b.x; d.y = a.y - b.y; d.z = a.z - b.z; d.w = a.w - b.w;
        if (x0 > 0)           dl = sr[row + x0 - 1] - hr[row + x0 - 1];
        if (x0 + 4 < IMG_W)   dr = sr[row + x0 + 4] - hr[row + x0 + 4];
    }
    // horizontal smooth [1,2,1] and diff [1,0,-1]
    s.x = dl  + 2.f * d.x + d.y;
    s.y = d.x + 2.f * d.y + d.z;
    s.z = d.y + 2.f * d.z + d.w;
    s.w = d.z + 2.f * d.w + dr;
    t.x = dl  - d.y;
    t.y = d.x - d.z;
    t.z = d.y - d.w;
    t.w = d.z - dr;
}

__global__ __launch_bounds__(256) void edge_loss_kernel(
        const float* __restrict__ sr, const float* __restrict__ hr,
        float* __restrict__ out, float invN) {
    const int chunk = blockIdx.x;
    const int b     = blockIdx.y;
    const int tid   = threadIdx.x;
    const int x0    = tid * 4;
    const size_t img_off = (size_t)b * IMG_H * IMG_W;
    const int y0 = chunk * CHUNK_H;

    float4 s0, s1, s2, t0, t1, t2;
    load_row(sr, hr, img_off, x0, y0 - 1, s0, t0);
    load_row(sr, hr, img_off, x0, y0,     s1, t1);

    float acc = 0.f;
    #pragma unroll 4
    for (int y = y0; y < y0 + CHUNK_H; ++y) {
        load_row(sr, hr, img_off, x0, y + 1, s2, t2);
        // gx = vertical smooth of t; gy = vertical diff of s
        float gx, gy;
        gx = t0.x + 2.f * t1.x + t2.x;  gy = s0.x - s2.x;  acc += fabsf(gx) + fabsf(gy);
        gx = t0.y + 2.f * t1.y + t2.y;  gy = s0.y - s2.y;  acc += fabsf(gx) + fabsf(gy);
        gx = t0.z + 2.f * t1.z + t2.z;  gy = s0.z - s2.z;  acc += fabsf(gx) + fabsf(gy);
        gx = t0.w + 2.f * t1.w + t2.w;  gy = s0.w - s2.w;  acc += fabsf(gx) + fabsf(gy);
        s0 = s1; t0 = t1; s1 = s2; t1 = t2;
    }

    // wave(64) shuffle reduction
    #pragma unroll
    for (int off = 32; off > 0; off >>= 1)
        acc += __shfl_down(acc, off, 64);

    __shared__ float wsum[4];
    const int wave = tid >> 6, lane = tid & 63;
    if (lane == 0) wsum[wave] = acc;
    __syncthreads();
    if (tid == 0) {
        float bsum = wsum[0] + wsum[1] + wsum[2] + wsum[3];
        atomicAdd(out, bsum * invN);
    }
}

extern "C" void kernel_launch(void* const* d_in, const int* in_sizes, int n_in,
                              void* d_out, int out_size, void* d_ws, size_t ws_size,
                              hipStream_t stream) {
    const float* sr = (const float*)d_in[0];
    const float* hr = (const float*)d_in[1];
    float* out = (float*)d_out;

    hipMemsetAsync(out, 0, sizeof(float), stream);

    dim3 grid(NCHUNK, IMG_B);
    const float invN = 1.0f / (float)((size_t)IMG_B * IMG_H * IMG_W);
    edge_loss_kernel<<<grid, 256, 0, stream>>>(sr, hr, out, invN);
}

// Round 2
// 282.986 us; speedup vs baseline: 1.0059x; 1.0059x over previous
//
#include <hip/hip_runtime.h>

// EdgeLoss: mean(|sobel_x(sr)-sobel_x(hr)| + |sobel_y(sr)-sobel_y(hr)|)
// = mean(|sobel_x(d)| + |sobel_y(d)|), d = sr - hr (conv is linear; the
// 180-deg flip of the sobel taps only flips sign, erased by abs).
// Separable: s = [1,2,1]*d (horiz), t = [1,0,-1]*d (horiz);
//            gx = [1,2,1]^T * t (vert), gy = [1,0,-1]^T * s (vert).
// 3-row register sliding window, 2-row explicit load-ahead, branch-free body.

#define IMG_H 1024
#define IMG_W 1024
#define IMG_B 32
#define CHUNK_H 16                 // output rows per block
#define NCHUNK (IMG_H / CHUNK_H)   // 64 -> 2048 blocks -> 8 blocks/CU

struct Raw { float4 a, b; float aL, bL, aR, bR; };

__device__ __forceinline__ Raw load_raw(const float* __restrict__ sr,
                                        const float* __restrict__ hr,
                                        size_t img, int yin, int x0, int lane) {
    // Row index clamped so the address is always valid; logically-out-of-image
    // rows are zeroed later via the mask in process(). Keeps loads branch-free.
    const int yc = min(max(yin, 0), IMG_H - 1);
    const size_t row = img + (size_t)yc * IMG_W;
    Raw r;
    r.a = *reinterpret_cast<const float4*>(sr + row + x0);
    r.b = *reinterpret_cast<const float4*>(hr + row + x0);
    r.aL = 0.f; r.bL = 0.f; r.aR = 0.f; r.bR = 0.f;
    // Wave-boundary halo: only lane 0 / lane 63 need a real load (2 lanes/wave).
    if (lane == 0 && x0 > 0)          { r.aL = sr[row + x0 - 1]; r.bL = hr[row + x0 - 1]; }
    if (lane == 63 && x0 + 4 < IMG_W) { r.aR = sr[row + x0 + 4]; r.bR = hr[row + x0 + 4]; }
    return r;
}

__device__ __forceinline__ Raw zero_raw() {
    Raw r;
    r.a = make_float4(0.f, 0.f, 0.f, 0.f);
    r.b = make_float4(0.f, 0.f, 0.f, 0.f);
    r.aL = r.bL = r.aR = r.bR = 0.f;
    return r;
}

// m = 0 zeroes logically-out-of-image rows (branch-free boundary handling).
__device__ __forceinline__ void process(const Raw& r, float m, int lane,
                                        float4& s, float4& t) {
    float4 d;
    d.x = (r.a.x - r.b.x) * m;
    d.y = (r.a.y - r.b.y) * m;
    d.z = (r.a.z - r.b.z) * m;
    d.w = (r.a.w - r.b.w) * m;
    float dl = __shfl_up(d.w, 1, 64);    // neighbor lane's last column
    float dr = __shfl_down(d.x, 1, 64);  // neighbor lane's first column
    if (lane == 0)  dl = (r.aL - r.bL) * m;
    if (lane == 63) dr = (r.aR - r.bR) * m;
    s.x = dl  + 2.f * d.x + d.y;
    s.y = d.x + 2.f * d.y + d.z;
    s.z = d.y + 2.f * d.z + d.w;
    s.w = d.z + 2.f * d.w + dr;
    t.x = dl  - d.y;
    t.y = d.x - d.z;
    t.z = d.y - d.w;
    t.w = d.z - dr;
}

__global__ __launch_bounds__(256) void edge_loss_kernel(
        const float* __restrict__ sr, const float* __restrict__ hr,
        float* __restrict__ out, float invN) {
    const int chunk = blockIdx.x;
    const int b     = blockIdx.y;
    const int tid   = threadIdx.x;
    const int lane  = tid & 63;
    const int x0    = tid * 4;
    const size_t img = (size_t)b * IMG_H * IMG_W;
    const int y0 = chunk * CHUNK_H;

    // Preamble: rows y0-1, y0 processed now; rows y0+1, y0+2 left in flight.
    Raw rm = load_raw(sr, hr, img, y0 - 1, x0, lane);
    Raw r0 = load_raw(sr, hr, img, y0,     x0, lane);
    Raw rA = load_raw(sr, hr, img, y0 + 1, x0, lane);
    Raw rB = load_raw(sr, hr, img, y0 + 2, x0, lane);

    float4 s0, t0, s1, t1, s2, t2;
    process(rm, (y0 > 0) ? 1.f : 0.f, lane, s0, t0);
    process(r0, 1.f, lane, s1, t1);

    float acc = 0.f;
    #pragma unroll
    for (int y = y0; y < y0 + CHUNK_H; ++y) {
        // Prefetch row y+3 (2-deep pipeline). Predicate folds at compile time
        // after unrolling (y - y0 is a constant per unrolled body).
        Raw rn = (y + 3 <= y0 + CHUNK_H)
                     ? load_raw(sr, hr, img, y + 3, x0, lane)
                     : zero_raw();
        // Consume row y+1 (loaded 2 iterations ago).
        process(rA, (y + 1 < IMG_H) ? 1.f : 0.f, lane, s2, t2);

        float gx, gy;
        gx = t0.x + 2.f * t1.x + t2.x;  gy = s0.x - s2.x;  acc += fabsf(gx) + fabsf(gy);
        gx = t0.y + 2.f * t1.y + t2.y;  gy = s0.y - s2.y;  acc += fabsf(gx) + fabsf(gy);
        gx = t0.z + 2.f * t1.z + t2.z;  gy = s0.z - s2.z;  acc += fabsf(gx) + fabsf(gy);
        gx = t0.w + 2.f * t1.w + t2.w;  gy = s0.w - s2.w;  acc += fabsf(gx) + fabsf(gy);

        s0 = s1; t0 = t1; s1 = s2; t1 = t2;
        rA = rB; rB = rn;
    }

    // wave(64) shuffle reduction, then cross-wave via LDS, one atomic/block
    #pragma unroll
    for (int off = 32; off > 0; off >>= 1)
        acc += __shfl_down(acc, off, 64);

    __shared__ float wsum[4];
    const int wave = tid >> 6;
    if (lane == 0) wsum[wave] = acc;
    __syncthreads();
    if (tid == 0) {
        float bsum = wsum[0] + wsum[1] + wsum[2] + wsum[3];
        atomicAdd(out, bsum * invN);
    }
}

extern "C" void kernel_launch(void* const* d_in, const int* in_sizes, int n_in,
                              void* d_out, int out_size, void* d_ws, size_t ws_size,
                              hipStream_t stream) {
    const float* sr = (const float*)d_in[0];
    const float* hr = (const float*)d_in[1];
    float* out = (float*)d_out;

    hipMemsetAsync(out, 0, sizeof(float), stream);

    dim3 grid(NCHUNK, IMG_B);
    const float invN = 1.0f / (float)((size_t)IMG_B * IMG_H * IMG_W);
    edge_loss_kernel<<<grid, 256, 0, stream>>>(sr, hr, out, invN);
}

// Round 3
// 275.697 us; speedup vs baseline: 1.0325x; 1.0264x over previous
//
#include <hip/hip_runtime.h>

// EdgeLoss: mean(|sobel_x(sr)-sobel_x(hr)| + |sobel_y(sr)-sobel_y(hr)|)
// = mean(|sobel_x(d)| + |sobel_y(d)|), d = sr - hr (conv linearity; the
// 180-deg kernel flip only flips sign, erased by abs).
// Separable: s = [1,2,1]*d (horiz), t = [1,0,-1]*d (horiz);
//            gx = [1,2,1]^T * t (vert), gy = [1,0,-1]^T * s (vert).
//
// R3 structure: BATCH-LOAD the whole chunk (10 rows x 2 arrays of float4)
// into register arrays in one unrolled loop -> 20+ loads in flight per wave
// (R2 post-mortem: VGPR=40 proved the compiler collapsed the rolling
// pipeline to MLP~1; this idiom forces it to hold the batch live).

#define IMG_H 1024
#define IMG_W 1024
#define IMG_B 32
#define CH 8                    // output rows per block
#define NROW (CH + 2)           // rows loaded (with vertical halo)
#define NCHUNK (IMG_H / CH)     // 128 -> grid 4096 blocks

__device__ __forceinline__ void row_st(const float4& a, const float4& b,
                                       float ha, float hb, float m, float hm,
                                       int lane, float4& s, float4& t) {
    float4 d;
    d.x = (a.x - b.x) * m;
    d.y = (a.y - b.y) * m;
    d.z = (a.z - b.z) * m;
    d.w = (a.w - b.w) * m;
    const float dh = (ha - hb) * (m * hm);   // boundary-lane halo d (0 at image edge)
    float dl = __shfl_up(d.w, 1, 64);        // left neighbor's last col
    float dr = __shfl_down(d.x, 1, 64);      // right neighbor's first col
    if (lane == 0)  dl = dh;
    if (lane == 63) dr = dh;
    s.x = dl  + 2.f * d.x + d.y;
    s.y = d.x + 2.f * d.y + d.z;
    s.z = d.y + 2.f * d.z + d.w;
    s.w = d.z + 2.f * d.w + dr;
    t.x = dl  - d.y;
    t.y = d.x - d.z;
    t.z = d.y - d.w;
    t.w = d.z - dr;
}

__global__ __launch_bounds__(256) void edge_loss_kernel(
        const float* __restrict__ sr, const float* __restrict__ hr,
        float* __restrict__ out, float invN) {
    const int chunk = blockIdx.x;
    const int b     = blockIdx.y;
    const int tid   = threadIdx.x;
    const int lane  = tid & 63;
    const int x0    = tid * 4;
    const size_t img = (size_t)b * IMG_H * IMG_W;
    const int y0 = chunk * CH;

    // Halo column for wave-boundary lanes (lanes 0 and 63): one scalar per row.
    const bool isL = (lane == 0);
    const bool isR = (lane == 63);
    const int  hx  = isL ? x0 - 1 : x0 + 4;
    const float hm = (isL ? (x0 > 0) : (x0 + 4 < IMG_W)) ? 1.f : 0.f;
    const int  hxc = min(max(hx, 0), IMG_W - 1);

    // ---- batch load phase: everything in flight at once ----
    float4 A[NROW], B[NROW];
    float  hA[NROW], hB[NROW];
    #pragma unroll
    for (int i = 0; i < NROW; ++i) { hA[i] = 0.f; hB[i] = 0.f; }

    #pragma unroll
    for (int i = 0; i < NROW; ++i) {
        const int yc = min(max(y0 - 1 + i, 0), IMG_H - 1);  // clamp, mask later
        const size_t row = img + (size_t)yc * IMG_W;
        A[i] = *reinterpret_cast<const float4*>(sr + row + x0);
        B[i] = *reinterpret_cast<const float4*>(hr + row + x0);
    }
    if (isL || isR) {            // exec-masked: only 2 lanes/wave issue these
        #pragma unroll
        for (int i = 0; i < NROW; ++i) {
            const int yc = min(max(y0 - 1 + i, 0), IMG_H - 1);
            const size_t row = img + (size_t)yc * IMG_W;
            hA[i] = sr[row + hxc];
            hB[i] = hr[row + hxc];
        }
    }

    // ---- compute phase: 3-row sliding s/t window over the register batch ----
    const float mtop = (y0 > 0) ? 1.f : 0.f;
    const float mbot = (y0 + CH < IMG_H) ? 1.f : 0.f;

    float4 s0, t0, s1, t1, s2, t2;
    row_st(A[0], B[0], hA[0], hB[0], mtop, hm, lane, s0, t0);
    row_st(A[1], B[1], hA[1], hB[1], 1.f,  hm, lane, s1, t1);

    float acc = 0.f;
    #pragma unroll
    for (int i = 2; i < NROW; ++i) {
        const float m = (i == NROW - 1) ? mbot : 1.f;
        row_st(A[i], B[i], hA[i], hB[i], m, hm, lane, s2, t2);

        float gx, gy;
        gx = t0.x + 2.f * t1.x + t2.x;  gy = s0.x - s2.x;  acc += fabsf(gx) + fabsf(gy);
        gx = t0.y + 2.f * t1.y + t2.y;  gy = s0.y - s2.y;  acc += fabsf(gx) + fabsf(gy);
        gx = t0.z + 2.f * t1.z + t2.z;  gy = s0.z - s2.z;  acc += fabsf(gx) + fabsf(gy);
        gx = t0.w + 2.f * t1.w + t2.w;  gy = s0.w - s2.w;  acc += fabsf(gx) + fabsf(gy);

        s0 = s1; t0 = t1; s1 = s2; t1 = t2;
    }

    // ---- reduction: wave shuffle -> LDS across 4 waves -> 1 atomic/block ----
    #pragma unroll
    for (int off = 32; off > 0; off >>= 1)
        acc += __shfl_down(acc, off, 64);

    __shared__ float wsum[4];
    const int wave = tid >> 6;
    if (lane == 0) wsum[wave] = acc;
    __syncthreads();
    if (tid == 0) {
        const float bsum = wsum[0] + wsum[1] + wsum[2] + wsum[3];
        atomicAdd(out, bsum * invN);
    }
}

extern "C" void kernel_launch(void* const* d_in, const int* in_sizes, int n_in,
                              void* d_out, int out_size, void* d_ws, size_t ws_size,
                              hipStream_t stream) {
    const float* sr = (const float*)d_in[0];
    const float* hr = (const float*)d_in[1];
    float* out = (float*)d_out;

    hipMemsetAsync(out, 0, sizeof(float), stream);

    dim3 grid(NCHUNK, IMG_B);
    const float invN = 1.0f / (float)((size_t)IMG_B * IMG_H * IMG_W);
    edge_loss_kernel<<<grid, 256, 0, stream>>>(sr, hr, out, invN);
}

// Round 4
// 273.697 us; speedup vs baseline: 1.0400x; 1.0073x over previous
//
#include <hip/hip_runtime.h>

// EdgeLoss: mean(|sobel_x(sr)-sobel_x(hr)| + |sobel_y(sr)-sobel_y(hr)|)
// = mean(|sobel_x(d)| + |sobel_y(d)|), d = sr - hr (conv linearity; the
// 180-deg kernel flip only flips sign, erased by abs).
// Separable: s = [1,2,1]*d (horiz), t = [1,0,-1]*d (horiz);
//            gx = [1,2,1]^T * t (vert), gy = [1,0,-1]^T * s (vert).
//
// R4: R3's batch-load, plus the two pins the R3 post-mortem demands:
//  - __launch_bounds__(256, 2): raise VGPR budget (R3's VGPR=64 proved the
//    scheduler sank the batch to hit the 8-wave occupancy bucket).
//  - sched_barrier(0) between load and compute phases: forbid re-sinking.
// Goal: all ~22 KB/wave of loads issued back-to-back -> one latency
// exposure per chunk, BW-bound operation.

#define IMG_H 1024
#define IMG_W 1024
#define IMG_B 32
#define CH 8                    // output rows per block
#define NROW (CH + 2)           // rows loaded (with vertical halo)
#define NCHUNK (IMG_H / CH)     // 128 -> grid 4096 blocks

__device__ __forceinline__ void row_st(const float4& a, const float4& b,
                                       float ha, float hb, float m, float hm,
                                       int lane, float4& s, float4& t) {
    float4 d;
    d.x = (a.x - b.x) * m;
    d.y = (a.y - b.y) * m;
    d.z = (a.z - b.z) * m;
    d.w = (a.w - b.w) * m;
    const float dh = (ha - hb) * (m * hm);   // boundary-lane halo d (0 at image edge)
    float dl = __shfl_up(d.w, 1, 64);        // left neighbor's last col
    float dr = __shfl_down(d.x, 1, 64);      // right neighbor's first col
    if (lane == 0)  dl = dh;
    if (lane == 63) dr = dh;
    s.x = dl  + 2.f * d.x + d.y;
    s.y = d.x + 2.f * d.y + d.z;
    s.z = d.y + 2.f * d.z + d.w;
    s.w = d.z + 2.f * d.w + dr;
    t.x = dl  - d.y;
    t.y = d.x - d.z;
    t.z = d.y - d.w;
    t.w = d.z - dr;
}

__global__ __launch_bounds__(256, 2) void edge_loss_kernel(
        const float* __restrict__ sr, const float* __restrict__ hr,
        float* __restrict__ out, float invN) {
    const int chunk = blockIdx.x;
    const int b     = blockIdx.y;
    const int tid   = threadIdx.x;
    const int lane  = tid & 63;
    const int x0    = tid * 4;
    const size_t img = (size_t)b * IMG_H * IMG_W;
    const int y0 = chunk * CH;

    // Halo column for wave-boundary lanes (lanes 0 and 63): one scalar per row.
    const bool isL = (lane == 0);
    const bool isR = (lane == 63);
    const int  hx  = isL ? x0 - 1 : x0 + 4;
    const float hm = (isL ? (x0 > 0) : (x0 + 4 < IMG_W)) ? 1.f : 0.f;
    const int  hxc = min(max(hx, 0), IMG_W - 1);

    // ---- batch load phase: everything issued before any consumption ----
    float4 A[NROW], B[NROW];
    float  hA[NROW], hB[NROW];
    #pragma unroll
    for (int i = 0; i < NROW; ++i) { hA[i] = 0.f; hB[i] = 0.f; }

    #pragma unroll
    for (int i = 0; i < NROW; ++i) {
        const int yc = min(max(y0 - 1 + i, 0), IMG_H - 1);  // clamp, mask later
        const size_t row = img + (size_t)yc * IMG_W;
        A[i] = *reinterpret_cast<const float4*>(sr + row + x0);
        B[i] = *reinterpret_cast<const float4*>(hr + row + x0);
    }
    if (isL || isR) {            // exec-masked: only 2 lanes/wave issue these
        #pragma unroll
        for (int i = 0; i < NROW; ++i) {
            const int yc = min(max(y0 - 1 + i, 0), IMG_H - 1);
            const size_t row = img + (size_t)yc * IMG_W;
            hA[i] = sr[row + hxc];
            hB[i] = hr[row + hxc];
        }
    }

    // Hard phase boundary: nothing (in particular the loads above) may be
    // moved across this point by the scheduler.
    __builtin_amdgcn_sched_barrier(0);

    // ---- compute phase: 3-row sliding s/t window over the register batch ----
    const float mtop = (y0 > 0) ? 1.f : 0.f;
    const float mbot = (y0 + CH < IMG_H) ? 1.f : 0.f;

    float4 s0, t0, s1, t1, s2, t2;
    row_st(A[0], B[0], hA[0], hB[0], mtop, hm, lane, s0, t0);
    row_st(A[1], B[1], hA[1], hB[1], 1.f,  hm, lane, s1, t1);

    float acc = 0.f;
    #pragma unroll
    for (int i = 2; i < NROW; ++i) {
        const float m = (i == NROW - 1) ? mbot : 1.f;
        row_st(A[i], B[i], hA[i], hB[i], m, hm, lane, s2, t2);

        float gx, gy;
        gx = t0.x + 2.f * t1.x + t2.x;  gy = s0.x - s2.x;  acc += fabsf(gx) + fabsf(gy);
        gx = t0.y + 2.f * t1.y + t2.y;  gy = s0.y - s2.y;  acc += fabsf(gx) + fabsf(gy);
        gx = t0.z + 2.f * t1.z + t2.z;  gy = s0.z - s2.z;  acc += fabsf(gx) + fabsf(gy);
        gx = t0.w + 2.f * t1.w + t2.w;  gy = s0.w - s2.w;  acc += fabsf(gx) + fabsf(gy);

        s0 = s1; t0 = t1; s1 = s2; t1 = t2;
    }

    // ---- reduction: wave shuffle -> LDS across 4 waves -> 1 atomic/block ----
    #pragma unroll
    for (int off = 32; off > 0; off >>= 1)
        acc += __shfl_down(acc, off, 64);

    __shared__ float wsum[4];
    const int wave = tid >> 6;
    if (lane == 0) wsum[wave] = acc;
    __syncthreads();
    if (tid == 0) {
        const float bsum = wsum[0] + wsum[1] + wsum[2] + wsum[3];
        atomicAdd(out, bsum * invN);
    }
}

extern "C" void kernel_launch(void* const* d_in, const int* in_sizes, int n_in,
                              void* d_out, int out_size, void* d_ws, size_t ws_size,
                              hipStream_t stream) {
    const float* sr = (const float*)d_in[0];
    const float* hr = (const float*)d_in[1];
    float* out = (float*)d_out;

    hipMemsetAsync(out, 0, sizeof(float), stream);

    dim3 grid(NCHUNK, IMG_B);
    const float invN = 1.0f / (float)((size_t)IMG_B * IMG_H * IMG_W);
    edge_loss_kernel<<<grid, 256, 0, stream>>>(sr, hr, out, invN);
}